// Round 2
// 757.050 us; speedup vs baseline: 1.0302x; 1.0302x over previous
//
#include <hip/hip_runtime.h>
#include <hip/hip_bf16.h>

typedef __bf16 bf16;
typedef __attribute__((ext_vector_type(4))) int intx4;
typedef __attribute__((ext_vector_type(4))) float floatx4;

__device__ __forceinline__ float b2f(unsigned short u) {
  union { unsigned int i; float f; } v; v.i = ((unsigned int)u) << 16; return v.f;
}

__device__ __forceinline__ void async_copy16(const void* g, void* l) {
  __builtin_amdgcn_global_load_lds((__attribute__((address_space(1))) void*)(g),
                                   (__attribute__((address_space(3))) void*)(l),
                                   16, 0, 0);
}

__device__ __forceinline__ float warp_sum(float v) {
  #pragma unroll
  for (int off = 32; off > 0; off >>= 1) v += __shfl_xor(v, off, 64);
  return v;
}
__device__ __forceinline__ float warp_max(float v) {
  #pragma unroll
  for (int off = 32; off > 0; off >>= 1) v = fmaxf(v, __shfl_xor(v, off, 64));
  return v;
}

// exact-erf GELU via A&S 7.1.26 (|eps| <= 1.5e-7), hw rcp + exp
__device__ __forceinline__ float gelu_fast(float v) {
  const float a = fabsf(v) * 0.70710678118654752440f;
  const float t = __builtin_amdgcn_rcpf(fmaf(0.3275911f, a, 1.0f));
  const float e = __expf(-a * a);
  float p = fmaf(1.061405429f, t, -1.453152027f);
  p = fmaf(p, t, 1.421413741f);
  p = fmaf(p, t, -0.284496736f);
  p = fmaf(p, t, 0.254829592f);
  float erfa = fmaf(-p * t, e, 1.0f);          // erf(|v|/sqrt2)
  erfa = copysignf(erfa, v);
  return 0.5f * v * (1.0f + erfa);
}

__device__ __forceinline__ void load4(const float* p, float* v) {
  float4 u = *(const float4*)p;
  v[0] = u.x; v[1] = u.y; v[2] = u.z; v[3] = u.w;
}
__device__ __forceinline__ void load4(const bf16* p, float* v) {
  ushort4 u = *(const ushort4*)p;
  v[0] = b2f(u.x); v[1] = b2f(u.y); v[2] = b2f(u.z); v[3] = b2f(u.w);
}

// ---------------- weight absmean (per-tensor, fp32 input) ----------------
__global__ __launch_bounds__(256) void absmean_partial(const float* __restrict__ w, int n,
                                                       float* __restrict__ partial) {
  const int tid = threadIdx.x;
  const int lane = tid & 63, wave = tid >> 6;
  float s = 0.f;
  for (size_t i = ((size_t)blockIdx.x * 256 + tid) * 4; i < (size_t)n;
       i += (size_t)256 * 256 * 4) {
    float4 u = *(const float4*)(w + i);
    s += fabsf(u.x) + fabsf(u.y) + fabsf(u.z) + fabsf(u.w);
  }
  __shared__ float red[4];
  s = warp_sum(s);
  if (lane == 0) red[wave] = s;
  __syncthreads();
  if (tid == 0) partial[blockIdx.x] = red[0] + red[1] + red[2] + red[3];
}

// scales: [0]=s_w1 (quant), [1]=dq_w1, [2]=s_w2, [3]=dq_w2
__global__ __launch_bounds__(256) void finalize_scales(const float* __restrict__ p1,
                                                       const float* __restrict__ p2,
                                                       float inv_n1, float inv_n2,
                                                       float* __restrict__ scales) {
  const int tid = threadIdx.x;
  const int lane = tid & 63, wave = tid >> 6;
  float a = p1[tid], b = p2[tid];
  a = warp_sum(a); b = warp_sum(b);
  __shared__ float red[8];
  if (lane == 0) { red[wave] = a; red[4 + wave] = b; }
  __syncthreads();
  if (tid == 0) {
    float m1 = fmaxf((red[0] + red[1] + red[2] + red[3]) * inv_n1, 1e-5f);
    float m2 = fmaxf((red[4] + red[5] + red[6] + red[7]) * inv_n2, 1e-5f);
    scales[0] = 1.0f / m1; scales[1] = m1;
    scales[2] = 1.0f / m2; scales[3] = m2;
  }
}

// ternarize fp32 weights -> int8 {-1,0,1}
__global__ __launch_bounds__(256) void quant_w(const float* __restrict__ w,
                                               signed char* __restrict__ wq,
                                               const float* __restrict__ sptr, int n) {
  const int i4 = (blockIdx.x * 256 + threadIdx.x) * 4;
  if (i4 >= n) return;
  const float s = *sptr;
  float4 u = *(const float4*)(w + i4);
  char4 o;
  o.x = (signed char)fminf(fmaxf(rintf(u.x * s), -1.f), 1.f);
  o.y = (signed char)fminf(fmaxf(rintf(u.y * s), -1.f), 1.f);
  o.z = (signed char)fminf(fmaxf(rintf(u.z * s), -1.f), 1.f);
  o.w = (signed char)fminf(fmaxf(rintf(u.w * s), -1.f), 1.f);
  *(char4*)(wq + i4) = o;
}

// ---------------- [gelu] + layernorm + per-row int8 quant ----------------
// one block per row; q may alias x rows (in-place): row fully read into regs
// before first barrier, written after second. px = input pitch (XT elems),
// pq = output pitch (bytes).
template <int D, bool GELU, typename XT>
__global__ __launch_bounds__(256) void ln_quant_kernel(const XT* __restrict__ x,
                                                       const float* __restrict__ gam,
                                                       const float* __restrict__ bet,
                                                       signed char* __restrict__ q,
                                                       float* __restrict__ rdq,
                                                       int px, int pq) {
  constexpr int NC = D / 1024;
  const int tid = threadIdx.x;
  const int lane = tid & 63, wave = tid >> 6;
  const size_t xbase = (size_t)blockIdx.x * px;
  const size_t qbase = (size_t)blockIdx.x * pq;
  float y[NC * 4];
  float s = 0.f, ss = 0.f;
  #pragma unroll
  for (int c = 0; c < NC; ++c) {
    const int idx = (c * 256 + tid) * 4;
    float v[4];
    load4(x + xbase + idx, v);
    #pragma unroll
    for (int j = 0; j < 4; ++j) {
      float vv = GELU ? gelu_fast(v[j]) : v[j];
      y[c * 4 + j] = vv; s += vv; ss += vv * vv;
    }
  }
  __shared__ float red[12];
  float sw = warp_sum(s), qw = warp_sum(ss);
  if (lane == 0) { red[wave] = sw; red[4 + wave] = qw; }
  __syncthreads();
  const float inv_d = 1.0f / (float)D;
  const float mu = (red[0] + red[1] + red[2] + red[3]) * inv_d;
  const float var = (red[4] + red[5] + red[6] + red[7]) * inv_d - mu * mu;
  const float rstd = rsqrtf(var + 1e-5f);
  float amax = 0.f;
  #pragma unroll
  for (int c = 0; c < NC; ++c) {
    const int idx = (c * 256 + tid) * 4;
    float4 gv = *(const float4*)(gam + idx);
    float4 bv = *(const float4*)(bet + idx);
    float gg[4] = {gv.x, gv.y, gv.z, gv.w};
    float bb[4] = {bv.x, bv.y, bv.z, bv.w};
    #pragma unroll
    for (int j = 0; j < 4; ++j) {
      float yy = (y[c * 4 + j] - mu) * rstd * gg[j] + bb[j];
      y[c * 4 + j] = yy;
      amax = fmaxf(amax, fabsf(yy));
    }
  }
  float wm = warp_max(amax);
  if (lane == 0) red[8 + wave] = wm;
  __syncthreads();
  const float am = fmaxf(fmaxf(fmaxf(red[8], red[9]), fmaxf(red[10], red[11])), 1e-5f);
  const float sc = 127.0f / am;
  #pragma unroll
  for (int c = 0; c < NC; ++c) {
    const int idx = (c * 256 + tid) * 4;
    char4 o;
    o.x = (signed char)fminf(fmaxf(rintf(y[c * 4 + 0] * sc), -128.f), 127.f);
    o.y = (signed char)fminf(fmaxf(rintf(y[c * 4 + 1] * sc), -128.f), 127.f);
    o.z = (signed char)fminf(fmaxf(rintf(y[c * 4 + 2] * sc), -128.f), 127.f);
    o.w = (signed char)fminf(fmaxf(rintf(y[c * 4 + 3] * sc), -128.f), 127.f);
    *(char4*)(q + qbase + idx) = o;
  }
  if (tid == 0) rdq[blockIdx.x] = am * (1.0f / 127.0f);
}

// ---------------- int8 GEMM: C[M,N] = A[M,K] * B[N,K]^T ----------------
// mfma_i32_16x16x64_i8; A pitch lda bytes, B pitch KB bytes, C pitch ldc elems.
// 128x128 tile, BK=64 bytes. Changes vs m97-style baseline:
//  - T1: XCD-chunked blockIdx swizzle (grid %8 == 0 at both call sites)
//  - T2: both-sides XOR swizzle (pre-swizzled per-lane GLOBAL source slot +
//        same XOR on ds_read addr; LDS dest stays linear for global_load_lds)
//  - T3/T4: double-buffered LDS, prefetch next K-tile before compute,
//        counted s_waitcnt vmcnt(4) + s_barrier (no vmcnt(0) drain in loop)
//  - T5: s_setprio(1) around the MFMA cluster

__device__ __forceinline__ void gemm_stage(const signed char* a0, const signed char* a1,
                                           const signed char* b0, const signed char* b1,
                                           int kb, signed char* lA, signed char* lB,
                                           int wave) {
  // LDS dest: hw adds lane*16; chunk ch lands at byte ch*16 (linear)
  async_copy16(a0 + kb, lA + wave * 2048);
  async_copy16(a1 + kb, lA + wave * 2048 + 1024);
  async_copy16(b0 + kb, lB + wave * 2048);
  async_copy16(b1 + kb, lB + wave * 2048 + 1024);
}

__device__ __forceinline__ void gemm_compute(const signed char* lA, const signed char* lB,
                                             int wm, int wn, int l16, int rsl,
                                             intx4 (&acc)[4][4]) {
  intx4 af[4], bfr[4];
  #pragma unroll
  for (int mi = 0; mi < 4; ++mi) {
    const int r = wm * 64 + mi * 16 + l16;
    af[mi] = *(const intx4*)&lA[r * 64 + rsl];
  }
  #pragma unroll
  for (int ni = 0; ni < 4; ++ni) {
    const int r = wn * 64 + ni * 16 + l16;
    bfr[ni] = *(const intx4*)&lB[r * 64 + rsl];
  }
  __builtin_amdgcn_s_setprio(1);
  #pragma unroll
  for (int mi = 0; mi < 4; ++mi)
    #pragma unroll
    for (int ni = 0; ni < 4; ++ni)
      acc[mi][ni] =
          __builtin_amdgcn_mfma_i32_16x16x64_i8(af[mi], bfr[ni], acc[mi][ni], 0, 0, 0);
  __builtin_amdgcn_s_setprio(0);
}

template <typename CT>
__global__ __launch_bounds__(256) void gemm_i8(const signed char* __restrict__ A,
                                               const signed char* __restrict__ B,
                                               CT* __restrict__ C,
                                               const float* __restrict__ rdq,
                                               const float* __restrict__ wdq_ptr,
                                               const float* __restrict__ bias,
                                               int N, int KB, int lda, int ldc) {
  __shared__ __align__(16) signed char lds[2][16384];  // [buf][A:0..8191 | B:8192..16383]
  const int tid = threadIdx.x;
  const int wave = tid >> 6, lane = tid & 63;
  const int quad = lane >> 4, l16 = lane & 15;
  const int nb = N >> 7;
  // T1: consecutive tile ids -> same XCD (blocks sharing the A panel hit one L2)
  const int cpx = (int)gridDim.x >> 3;
  const int wg = (int)blockIdx.x;
  const int tile = (wg & 7) * cpx + (wg >> 3);
  const int bm = tile / nb;
  const int bn = tile % nb;
  const int wm = wave & 1, wn = wave >> 1;

  // 512 16B chunks per operand tile; chunk ch = row*4 + slot. Global source slot
  // pre-swizzled: gs = slot ^ ((row>>1)&3) so that the linear LDS write + swizzled
  // ds_read are the same involution (rule 21). Note ch>>3 == row>>1 exactly.
  const int ch0 = wave * 128 + lane;
  const int ch1 = ch0 + 64;
  const int g0 = (((ch0 & 3) ^ ((ch0 >> 3) & 3)) * 16);
  const int g1 = (((ch1 & 3) ^ ((ch1 >> 3) & 3)) * 16);
  const signed char* a0 = A + (size_t)(bm * 128 + (ch0 >> 2)) * lda + g0;
  const signed char* a1 = A + (size_t)(bm * 128 + (ch1 >> 2)) * lda + g1;
  const signed char* b0 = B + (size_t)(bn * 128 + (ch0 >> 2)) * KB + g0;
  const signed char* b1 = B + (size_t)(bn * 128 + (ch1 >> 2)) * KB + g1;

  // read-side swizzled slot: s = quad ^ ((r>>1)&3); r = 16m + l16 -> (r>>1)&3 == (l16>>1)&3
  const int rsl = (quad ^ ((l16 >> 1) & 3)) * 16;

  intx4 acc[4][4];
  #pragma unroll
  for (int i = 0; i < 4; ++i)
    #pragma unroll
    for (int j = 0; j < 4; ++j) acc[i][j] = (intx4){0, 0, 0, 0};

  const float wdq = *wdq_ptr;
  const int NT = KB >> 6;

  // prologue: stage tile 0 into buf 0
  gemm_stage(a0, a1, b0, b1, 0, &lds[0][0], &lds[0][8192], wave);
  int cur = 0;
  for (int t = 0; t < NT - 1; ++t) {
    // prefetch next tile into the other buffer (its readers finished at the
    // trailing barrier of the previous iteration)
    gemm_stage(a0, a1, b0, b1, (t + 1) << 6, &lds[cur ^ 1][0], &lds[cur ^ 1][8192], wave);
    // wait own 4 current-tile copies (4 prefetch copies stay in flight), sync
    asm volatile("s_waitcnt vmcnt(4)" ::: "memory");
    __builtin_amdgcn_s_barrier();
    gemm_compute(&lds[cur][0], &lds[cur][8192], wm, wn, l16, rsl, acc);
    // ds_reads retired before buffers may be overwritten next iter
    asm volatile("s_waitcnt lgkmcnt(0)" ::: "memory");
    __builtin_amdgcn_s_barrier();
    cur ^= 1;
  }
  asm volatile("s_waitcnt vmcnt(0)" ::: "memory");
  __builtin_amdgcn_s_barrier();
  gemm_compute(&lds[cur][0], &lds[cur][8192], wm, wn, l16, rsl, acc);

  // epilogue: C/D layout col=lane&15, row=quad*4+reg (shape-determined, m121-128)
  #pragma unroll
  for (int mi = 0; mi < 4; ++mi) {
    const int rowb = bm * 128 + wm * 64 + mi * 16 + quad * 4;
    const floatx4 rd = *(const floatx4*)&rdq[rowb];
    #pragma unroll
    for (int ni = 0; ni < 4; ++ni) {
      const int col = bn * 128 + wn * 64 + ni * 16 + l16;
      const float bv = bias[col];
      #pragma unroll
      for (int r2 = 0; r2 < 4; ++r2) {
        float v = fmaf((float)acc[mi][ni][r2], rd[r2] * wdq, bv);
        C[(size_t)(rowb + r2) * ldc + col] = (CT)v;
      }
    }
  }
}

extern "C" void kernel_launch(void* const* d_in, const int* in_sizes, int n_in,
                              void* d_out, int out_size, void* d_ws, size_t ws_size,
                              hipStream_t stream) {
  (void)in_sizes; (void)n_in; (void)out_size; (void)ws_size;
  const float* x   = (const float*)d_in[0];
  const float* g1  = (const float*)d_in[1];
  const float* be1 = (const float*)d_in[2];
  const float* w1  = (const float*)d_in[3];
  const float* b1  = (const float*)d_in[4];
  const float* g2  = (const float*)d_in[5];
  const float* be2 = (const float*)d_in[6];
  const float* w2  = (const float*)d_in[7];
  const float* b2  = (const float*)d_in[8];
  float* out = (float*)d_out;

  const int BT = 8 * 4096, D = 1024, H = 4096;
  char* ws = (char*)d_ws;
  float* scales = (float*)(ws);                 // 4 floats
  float* p1     = (float*)(ws + 1024);
  float* p2     = (float*)(ws + 2048);
  float* rdq1   = (float*)(ws + 4096);          // 32768 fp32
  float* rdq2   = (float*)(ws + 4096 + 131072);
  char* big = ws + (1 << 20);
  signed char* w1q = (signed char*)(big);                 // 4 MB
  signed char* w2q = (signed char*)(big + (4 << 20));     // 4 MB
  signed char* qx1 = (signed char*)(big + (8 << 20));     // 32 MB
  bf16* h1 = (bf16*)(big + (40 << 20));                   // 256 MB -> total ~297 MB

  const int NW = H * D;
  absmean_partial<<<256, 256, 0, stream>>>(w1, NW, p1);
  absmean_partial<<<256, 256, 0, stream>>>(w2, NW, p2);
  finalize_scales<<<1, 256, 0, stream>>>(p1, p2, 1.0f / NW, 1.0f / NW, scales);
  quant_w<<<NW / 1024, 256, 0, stream>>>(w1, w1q, scales + 0, NW);
  quant_w<<<NW / 1024, 256, 0, stream>>>(w2, w2q, scales + 2, NW);

  // LN1 + act quant -> int8
  ln_quant_kernel<1024, false, float><<<BT, 256, 0, stream>>>(x, g1, be1, qx1, rdq1,
                                                              D, D);
  // GEMM1: h1(bf16) = dequant(qx1 . w1q^T) + b1   (pre-GELU; GELU fused into LN2)
  gemm_i8<bf16><<<(BT / 128) * (H / 128), 256, 0, stream>>>(
      qx1, w1q, h1, rdq1, scales + 1, b1, H, D, D, H);
  // GELU + LN2 + act quant, int8 written in-place into h1 row starts (pitch 8192 B)
  ln_quant_kernel<4096, true, bf16><<<BT, 256, 0, stream>>>(
      h1, g2, be2, (signed char*)h1, rdq2, H, 2 * H);
  // GEMM2: out(fp32) = dequant(q . w2q^T) + b2
  gemm_i8<float><<<(BT / 128) * (D / 128), 256, 0, stream>>>(
      (signed char*)h1, w2q, out, rdq2, scales + 3, b2, D, H, 2 * H, D);
}

// Round 3
// 678.056 us; speedup vs baseline: 1.1502x; 1.1165x over previous
//
#include <hip/hip_runtime.h>
#include <hip/hip_bf16.h>

typedef __bf16 bf16;
typedef __attribute__((ext_vector_type(4))) int intx4;
typedef __attribute__((ext_vector_type(4))) float floatx4;

__device__ __forceinline__ float b2f(unsigned short u) {
  union { unsigned int i; float f; } v; v.i = ((unsigned int)u) << 16; return v.f;
}

__device__ __forceinline__ void async_copy16(const void* g, void* l) {
  __builtin_amdgcn_global_load_lds((__attribute__((address_space(1))) void*)(g),
                                   (__attribute__((address_space(3))) void*)(l),
                                   16, 0, 0);
}

__device__ __forceinline__ float warp_sum(float v) {
  #pragma unroll
  for (int off = 32; off > 0; off >>= 1) v += __shfl_xor(v, off, 64);
  return v;
}
__device__ __forceinline__ float warp_max(float v) {
  #pragma unroll
  for (int off = 32; off > 0; off >>= 1) v = fmaxf(v, __shfl_xor(v, off, 64));
  return v;
}

// exact-erf GELU via A&S 7.1.26 (|eps| <= 1.5e-7), hw rcp + exp
__device__ __forceinline__ float gelu_fast(float v) {
  const float a = fabsf(v) * 0.70710678118654752440f;
  const float t = __builtin_amdgcn_rcpf(fmaf(0.3275911f, a, 1.0f));
  const float e = __expf(-a * a);
  float p = fmaf(1.061405429f, t, -1.453152027f);
  p = fmaf(p, t, 1.421413741f);
  p = fmaf(p, t, -0.284496736f);
  p = fmaf(p, t, 0.254829592f);
  float erfa = fmaf(-p * t, e, 1.0f);          // erf(|v|/sqrt2)
  erfa = copysignf(erfa, v);
  return 0.5f * v * (1.0f + erfa);
}

__device__ __forceinline__ void load4(const float* p, float* v) {
  float4 u = *(const float4*)p;
  v[0] = u.x; v[1] = u.y; v[2] = u.z; v[3] = u.w;
}
__device__ __forceinline__ void load4(const bf16* p, float* v) {
  ushort4 u = *(const ushort4*)p;
  v[0] = b2f(u.x); v[1] = b2f(u.y); v[2] = b2f(u.z); v[3] = b2f(u.w);
}

// ---------------- weight absmean (per-tensor, fp32 input) ----------------
__global__ __launch_bounds__(256) void absmean_partial(const float* __restrict__ w, int n,
                                                       float* __restrict__ partial) {
  const int tid = threadIdx.x;
  const int lane = tid & 63, wave = tid >> 6;
  float s = 0.f;
  for (size_t i = ((size_t)blockIdx.x * 256 + tid) * 4; i < (size_t)n;
       i += (size_t)256 * 256 * 4) {
    float4 u = *(const float4*)(w + i);
    s += fabsf(u.x) + fabsf(u.y) + fabsf(u.z) + fabsf(u.w);
  }
  __shared__ float red[4];
  s = warp_sum(s);
  if (lane == 0) red[wave] = s;
  __syncthreads();
  if (tid == 0) partial[blockIdx.x] = red[0] + red[1] + red[2] + red[3];
}

// scales: [0]=s_w1 (quant), [1]=dq_w1, [2]=s_w2, [3]=dq_w2
__global__ __launch_bounds__(256) void finalize_scales(const float* __restrict__ p1,
                                                       const float* __restrict__ p2,
                                                       float inv_n1, float inv_n2,
                                                       float* __restrict__ scales) {
  const int tid = threadIdx.x;
  const int lane = tid & 63, wave = tid >> 6;
  float a = p1[tid], b = p2[tid];
  a = warp_sum(a); b = warp_sum(b);
  __shared__ float red[8];
  if (lane == 0) { red[wave] = a; red[4 + wave] = b; }
  __syncthreads();
  if (tid == 0) {
    float m1 = fmaxf((red[0] + red[1] + red[2] + red[3]) * inv_n1, 1e-5f);
    float m2 = fmaxf((red[4] + red[5] + red[6] + red[7]) * inv_n2, 1e-5f);
    scales[0] = 1.0f / m1; scales[1] = m1;
    scales[2] = 1.0f / m2; scales[3] = m2;
  }
}

// ternarize fp32 weights -> int8 {-1,0,1}
__global__ __launch_bounds__(256) void quant_w(const float* __restrict__ w,
                                               signed char* __restrict__ wq,
                                               const float* __restrict__ sptr, int n) {
  const int i4 = (blockIdx.x * 256 + threadIdx.x) * 4;
  if (i4 >= n) return;
  const float s = *sptr;
  float4 u = *(const float4*)(w + i4);
  char4 o;
  o.x = (signed char)fminf(fmaxf(rintf(u.x * s), -1.f), 1.f);
  o.y = (signed char)fminf(fmaxf(rintf(u.y * s), -1.f), 1.f);
  o.z = (signed char)fminf(fmaxf(rintf(u.z * s), -1.f), 1.f);
  o.w = (signed char)fminf(fmaxf(rintf(u.w * s), -1.f), 1.f);
  *(char4*)(wq + i4) = o;
}

// ---------------- [gelu] + layernorm + per-row int8 quant ----------------
// one block per row; q may alias x rows (in-place): row fully read into regs
// before first barrier, written after second. px = input pitch (XT elems),
// pq = output pitch (bytes).
template <int D, bool GELU, typename XT>
__global__ __launch_bounds__(256) void ln_quant_kernel(const XT* __restrict__ x,
                                                       const float* __restrict__ gam,
                                                       const float* __restrict__ bet,
                                                       signed char* __restrict__ q,
                                                       float* __restrict__ rdq,
                                                       int px, int pq) {
  constexpr int NC = D / 1024;
  const int tid = threadIdx.x;
  const int lane = tid & 63, wave = tid >> 6;
  const size_t xbase = (size_t)blockIdx.x * px;
  const size_t qbase = (size_t)blockIdx.x * pq;
  float y[NC * 4];
  float s = 0.f, ss = 0.f;
  #pragma unroll
  for (int c = 0; c < NC; ++c) {
    const int idx = (c * 256 + tid) * 4;
    float v[4];
    load4(x + xbase + idx, v);
    #pragma unroll
    for (int j = 0; j < 4; ++j) {
      float vv = GELU ? gelu_fast(v[j]) : v[j];
      y[c * 4 + j] = vv; s += vv; ss += vv * vv;
    }
  }
  __shared__ float red[12];
  float sw = warp_sum(s), qw = warp_sum(ss);
  if (lane == 0) { red[wave] = sw; red[4 + wave] = qw; }
  __syncthreads();
  const float inv_d = 1.0f / (float)D;
  const float mu = (red[0] + red[1] + red[2] + red[3]) * inv_d;
  const float var = (red[4] + red[5] + red[6] + red[7]) * inv_d - mu * mu;
  const float rstd = rsqrtf(var + 1e-5f);
  float amax = 0.f;
  #pragma unroll
  for (int c = 0; c < NC; ++c) {
    const int idx = (c * 256 + tid) * 4;
    float4 gv = *(const float4*)(gam + idx);
    float4 bv = *(const float4*)(bet + idx);
    float gg[4] = {gv.x, gv.y, gv.z, gv.w};
    float bb[4] = {bv.x, bv.y, bv.z, bv.w};
    #pragma unroll
    for (int j = 0; j < 4; ++j) {
      float yy = (y[c * 4 + j] - mu) * rstd * gg[j] + bb[j];
      y[c * 4 + j] = yy;
      amax = fmaxf(amax, fabsf(yy));
    }
  }
  float wm = warp_max(amax);
  if (lane == 0) red[8 + wave] = wm;
  __syncthreads();
  const float am = fmaxf(fmaxf(fmaxf(red[8], red[9]), fmaxf(red[10], red[11])), 1e-5f);
  const float sc = 127.0f / am;
  #pragma unroll
  for (int c = 0; c < NC; ++c) {
    const int idx = (c * 256 + tid) * 4;
    char4 o;
    o.x = (signed char)fminf(fmaxf(rintf(y[c * 4 + 0] * sc), -128.f), 127.f);
    o.y = (signed char)fminf(fmaxf(rintf(y[c * 4 + 1] * sc), -128.f), 127.f);
    o.z = (signed char)fminf(fmaxf(rintf(y[c * 4 + 2] * sc), -128.f), 127.f);
    o.w = (signed char)fminf(fmaxf(rintf(y[c * 4 + 3] * sc), -128.f), 127.f);
    *(char4*)(q + qbase + idx) = o;
  }
  if (tid == 0) rdq[blockIdx.x] = am * (1.0f / 127.0f);
}

// ---------------- int8 GEMM, 256x256 tile, 8-phase schedule ----------------
// C[M,N] = A[M,K] * B[N,K]^T, mfma_i32_16x16x64_i8. 512 threads = 8 waves (2M x 4N),
// per-wave 128x64 output. BK=128 bytes = 2 k-slots of 64. LDS 128KB:
// [buf(2)][A ks0|A ks1|B ks0|B ks1] regions of 16KB (k-slot-major so each region's
// readers are confined to 2 phases -> region free mid-tile for prefetch).
// Pipeline: 2 tiles deep; per phase stage exactly 1 half (2 gload_lds/thread):
//   P1: stage A-k1(t+1)   (region free since t-1's P4 barrier)
//   P2: stage B-k1(t+1)
//   P3: stage A-k0(t+2)   (A-k0(t) readers retired at P2 barrier)
//   P4: stage B-k0(t+2)   (B-k0(t) readers retired at P1 barrier)
// vmcnt(4) once per tile (before P4's trailing barrier): leaves the P3/P4 loads
// (2 halves = 4) in flight, guarantees tile t+1 fully landed. Tail uses vmcnt(0).
// Swizzle (verified round 2, conflicts -> 0): global source slot ^ ((row>>1)&3),
// linear LDS dest, ds_read slot quad ^ ((l16>>1)&3).

#define READ_A(MH, KS, BUF)                                                  \
  _Pragma("unroll") for (int mi = 0; mi < 4; ++mi) {                         \
    aR[mi] = *(const intx4*)&lds[(BUF) * 65536 + (KS) * 16384 + aoff +       \
                                 ((MH) * 4 + mi) * 1024];                    \
  }

#define READ_B(KS, BUF)                                                      \
  _Pragma("unroll") for (int ni = 0; ni < 4; ++ni) {                         \
    bR[ni] = *(const intx4*)&lds[(BUF) * 65536 + 32768 + (KS) * 16384 +      \
                                 boff + ni * 1024];                          \
  }

#define PHASE_MFMA(MH)                                                       \
  __builtin_amdgcn_s_barrier();                                              \
  asm volatile("s_waitcnt lgkmcnt(0)" ::: "memory");                         \
  __builtin_amdgcn_s_setprio(1);                                             \
  _Pragma("unroll") for (int mi = 0; mi < 4; ++mi) {                         \
    _Pragma("unroll") for (int ni = 0; ni < 4; ++ni) {                       \
      acc[(MH) * 4 + mi][ni] = __builtin_amdgcn_mfma_i32_16x16x64_i8(        \
          aR[mi], bR[ni], acc[(MH) * 4 + mi][ni], 0, 0, 0);                  \
    }                                                                        \
  }                                                                          \
  __builtin_amdgcn_s_setprio(0);

#define TILE_STEP(T, BUF, S1, S2, VM)                                        \
  do {                                                                       \
    READ_A(0, 0, BUF);                                                       \
    READ_B(0, BUF);                                                          \
    if (S1) { stageA((T) + 1, 1, (BUF) ^ 1); }                               \
    PHASE_MFMA(0);                                                           \
    __builtin_amdgcn_s_barrier();                                            \
    READ_A(1, 0, BUF);                                                       \
    if (S1) { stageB((T) + 1, 1, (BUF) ^ 1); }                               \
    PHASE_MFMA(1);                                                           \
    __builtin_amdgcn_s_barrier();                                            \
    READ_A(0, 1, BUF);                                                       \
    READ_B(1, BUF);                                                          \
    if (S2) { stageA((T) + 2, 0, BUF); }                                     \
    PHASE_MFMA(0);                                                           \
    __builtin_amdgcn_s_barrier();                                            \
    READ_A(1, 1, BUF);                                                       \
    if (S2) { stageB((T) + 2, 0, BUF); }                                     \
    PHASE_MFMA(1);                                                           \
    asm volatile("s_waitcnt vmcnt(" #VM ")" ::: "memory");                   \
    __builtin_amdgcn_s_barrier();                                            \
  } while (0)

template <typename CT>
__global__ __launch_bounds__(512, 2) void gemm_i8(const signed char* __restrict__ A,
                                                  const signed char* __restrict__ B,
                                                  CT* __restrict__ C,
                                                  const float* __restrict__ rdq,
                                                  const float* __restrict__ wdq_ptr,
                                                  const float* __restrict__ bias,
                                                  int N, int KB, int lda, int ldc) {
  __shared__ __align__(16) signed char lds[131072];
  const int tid = threadIdx.x;
  const int wave = tid >> 6, lane = tid & 63;
  const int quad = lane >> 4, l16 = lane & 15;
  const int nb = N >> 8;
  // T1: consecutive tile ids -> same XCD
  const int cpx = (int)gridDim.x >> 3;
  const int wg = (int)blockIdx.x;
  const int tile = (wg & 7) * cpx + (wg >> 3);
  const int bm = tile / nb;
  const int bn = tile % nb;
  const int wm = wave >> 2, wn = wave & 3;

  // staging: per half (16KB = 1024 chunks of 16B), thread handles chunks ch0, ch1.
  // chunk ch = row*4 + slot; global slot pre-swizzled: slot ^ ((row>>1)&3),
  // and (4*row+slot)>>3 == row>>1 exactly.
  const int ch0 = wave * 128 + lane;
  const int ch1 = ch0 + 64;
  const int g0 = ((ch0 & 3) ^ ((ch0 >> 3) & 3)) * 16;
  const int g1 = ((ch1 & 3) ^ ((ch1 >> 3) & 3)) * 16;
  const signed char* a0 = A + (size_t)(bm * 256 + (ch0 >> 2)) * lda + g0;
  const signed char* a1 = A + (size_t)(bm * 256 + (ch1 >> 2)) * lda + g1;
  const signed char* b0 = B + (size_t)(bn * 256 + (ch0 >> 2)) * KB + g0;
  const signed char* b1 = B + (size_t)(bn * 256 + (ch1 >> 2)) * KB + g1;

  auto stageA = [&](int t, int ks, int b) {
    signed char* d = &lds[b * 65536 + ks * 16384 + wave * 2048];
    const int off = t * 128 + ks * 64;
    async_copy16(a0 + off, d);
    async_copy16(a1 + off, d + 1024);
  };
  auto stageB = [&](int t, int ks, int b) {
    signed char* d = &lds[b * 65536 + 32768 + ks * 16384 + wave * 2048];
    const int off = t * 128 + ks * 64;
    async_copy16(b0 + off, d);
    async_copy16(b1 + off, d + 1024);
  };

  // ds_read addressing: row = (wm*128|wn*64) + (frag)*16 + l16; byte = row*64 + rsl.
  // row parity bits reduce to (l16>>1)&3 for every frag (others are 0 mod 4).
  const int rsl = (quad ^ ((l16 >> 1) & 3)) * 16;
  const int aoff = (wm * 128 + l16) * 64 + rsl;  // + (MH*4+mi)*1024
  const int boff = (wn * 64 + l16) * 64 + rsl;   // + ni*1024

  intx4 acc[8][4];
  #pragma unroll
  for (int i = 0; i < 8; ++i)
    #pragma unroll
    for (int j = 0; j < 4; ++j) acc[i][j] = (intx4){0, 0, 0, 0};
  intx4 aR[4], bR[4];

  const float wdq = *wdq_ptr;
  const int NT = KB >> 7;  // 128B K-tiles; NT even (8 or 32)

  // prologue: tile0 all 4 halves + tile1 k0 halves; leave tile1's 2 halves in flight
  stageA(0, 0, 0); stageB(0, 0, 0);
  stageA(0, 1, 0); stageB(0, 1, 0);
  stageA(1, 0, 1); stageB(1, 0, 1);
  asm volatile("s_waitcnt vmcnt(4)" ::: "memory");
  __builtin_amdgcn_s_barrier();

  for (int t = 0; t < NT - 2; t += 2) {
    TILE_STEP(t, 0, true, true, 4);
    TILE_STEP(t + 1, 1, true, true, 4);
  }
  TILE_STEP(NT - 2, 0, true, false, 0);
  TILE_STEP(NT - 1, 1, false, false, 0);

  // epilogue: C/D layout col=lane&15, row=quad*4+reg (shape-determined, m121-128)
  #pragma unroll
  for (int mi = 0; mi < 8; ++mi) {
    const int rowb = bm * 256 + wm * 128 + mi * 16 + quad * 4;
    const floatx4 rd = *(const floatx4*)&rdq[rowb];
    #pragma unroll
    for (int ni = 0; ni < 4; ++ni) {
      const int col = bn * 256 + wn * 64 + ni * 16 + l16;
      const float bv = bias[col];
      #pragma unroll
      for (int r2 = 0; r2 < 4; ++r2) {
        float v = fmaf((float)acc[mi][ni][r2], rd[r2] * wdq, bv);
        C[(size_t)(rowb + r2) * ldc + col] = (CT)v;
      }
    }
  }
}

extern "C" void kernel_launch(void* const* d_in, const int* in_sizes, int n_in,
                              void* d_out, int out_size, void* d_ws, size_t ws_size,
                              hipStream_t stream) {
  (void)in_sizes; (void)n_in; (void)out_size; (void)ws_size;
  const float* x   = (const float*)d_in[0];
  const float* g1  = (const float*)d_in[1];
  const float* be1 = (const float*)d_in[2];
  const float* w1  = (const float*)d_in[3];
  const float* b1  = (const float*)d_in[4];
  const float* g2  = (const float*)d_in[5];
  const float* be2 = (const float*)d_in[6];
  const float* w2  = (const float*)d_in[7];
  const float* b2  = (const float*)d_in[8];
  float* out = (float*)d_out;

  const int BT = 8 * 4096, D = 1024, H = 4096;
  char* ws = (char*)d_ws;
  float* scales = (float*)(ws);                 // 4 floats
  float* p1     = (float*)(ws + 1024);
  float* p2     = (float*)(ws + 2048);
  float* rdq1   = (float*)(ws + 4096);          // 32768 fp32
  float* rdq2   = (float*)(ws + 4096 + 131072);
  char* big = ws + (1 << 20);
  signed char* w1q = (signed char*)(big);                 // 4 MB
  signed char* w2q = (signed char*)(big + (4 << 20));     // 4 MB
  signed char* qx1 = (signed char*)(big + (8 << 20));     // 32 MB
  bf16* h1 = (bf16*)(big + (40 << 20));                   // 256 MB -> total ~297 MB

  const int NW = H * D;
  absmean_partial<<<256, 256, 0, stream>>>(w1, NW, p1);
  absmean_partial<<<256, 256, 0, stream>>>(w2, NW, p2);
  finalize_scales<<<1, 256, 0, stream>>>(p1, p2, 1.0f / NW, 1.0f / NW, scales);
  quant_w<<<NW / 1024, 256, 0, stream>>>(w1, w1q, scales + 0, NW);
  quant_w<<<NW / 1024, 256, 0, stream>>>(w2, w2q, scales + 2, NW);

  // LN1 + act quant -> int8
  ln_quant_kernel<1024, false, float><<<BT, 256, 0, stream>>>(x, g1, be1, qx1, rdq1,
                                                              D, D);
  // GEMM1: h1(bf16) = dequant(qx1 . w1q^T) + b1   (pre-GELU; GELU fused into LN2)
  gemm_i8<bf16><<<(BT / 256) * (H / 256), 512, 0, stream>>>(
      qx1, w1q, h1, rdq1, scales + 1, b1, H, D, D, H);
  // GELU + LN2 + act quant, int8 written in-place into h1 row starts (pitch 8192 B)
  ln_quant_kernel<4096, true, bf16><<<BT, 256, 0, stream>>>(
      h1, g2, be2, (signed char*)h1, rdq2, H, 2 * H);
  // GEMM2: out(fp32) = dequant(q . w2q^T) + b2
  gemm_i8<float><<<(BT / 256) * (D / 256), 512, 0, stream>>>(
      (signed char*)h1, w2q, out, rdq2, scales + 3, b2, D, H, 2 * H, D);
}